// Round 1
// baseline (238.097 us; speedup 1.0000x reference)
//
#include <hip/hip_runtime.h>
#include <math.h>

#define LSEQ 128
#define NLL 16384      // L*L
#define NBATCH 4
#define DIM 768
#define NB 4
#define ALPHA_C 32.0f
#define MRG_C 0.05f
#define CLW_C 0.05f

__device__ __forceinline__ float wave_reduce_f(float v) {
#pragma unroll
    for (int s = 1; s < 64; s <<= 1) v += __shfl_xor(v, s);
    return v;
}

__device__ __forceinline__ float dot4(float4 a, float4 b) {
    return a.x*b.x + a.y*b.y + a.z*b.z + a.w*b.w;
}

// One wave handles 8 consecutive rows of 768 floats.
// Grid: 2048 blocks x 256 threads = 8192 waves * 8 rows = 65536 rows.
template<bool EDGE>
__global__ __launch_bounds__(256)
void fused_pass(const float* __restrict__ table,
                const int*   __restrict__ labels,
                const int*   __restrict__ attn,
                const float* __restrict__ prox,
                const float* __restrict__ wS, const float* __restrict__ bS,
                const float* __restrict__ wE, const float* __restrict__ bE,
                const int*   __restrict__ tlabS, const int* __restrict__ tlabE,
                float* __restrict__ pS, float* __restrict__ pE,
                float* __restrict__ partial /* [8192][14] */)
{
    const int gtid = blockIdx.x * 256 + threadIdx.x;
    const int wave = gtid >> 6;
    const int lane = gtid & 63;
    const int row0 = wave * 8;
    const int b = row0 >> 14;   // 16384 rows per batch

    // lens[b] = sum(attention_mask[b])
    int lens_i = attn[b*LSEQ + lane] + attn[b*LSEQ + 64 + lane];
#pragma unroll
    for (int s = 1; s < 64; s <<= 1) lens_i += __shfl_xor(lens_i, s);

    // Preload proxies (this lane's slice) + proxy inverse norms
    float4 px[NB][3];
    float pinv[NB];
#pragma unroll
    for (int c = 0; c < NB; ++c) {
        float s2 = 0.f;
#pragma unroll
        for (int t = 0; t < 3; ++t) {
            px[c][t] = *reinterpret_cast<const float4*>(prox + c*DIM + t*256 + lane*4);
            s2 += dot4(px[c][t], px[c][t]);
        }
        s2 = wave_reduce_f(s2);
        pinv[c] = 1.0f / fmaxf(sqrtf(s2), 1e-12f);
    }
    float4 vs[3], ve[3];
    float bSv = 0.f, bEv = 0.f;
    if constexpr (EDGE) {
#pragma unroll
        for (int t = 0; t < 3; ++t) {
            vs[t] = *reinterpret_cast<const float4*>(wS + t*256 + lane*4);
            ve[t] = *reinterpret_cast<const float4*>(wE + t*256 + lane*4);
        }
        bSv = bS[0]; bEv = bE[0];
    }

    float accP[NB] = {0,0,0,0}, accN[NB] = {0,0,0,0}, accC[NB] = {0,0,0,0};
    float accBS = 0.f, accBE = 0.f;

    for (int rr = 0; rr < 8; ++rr) {
        const int r = row0 + rr;
        const float* xb = table + (size_t)r * DIM;
        float xx = 0.f, d0 = 0.f, d1 = 0.f, d2 = 0.f, d3 = 0.f, dS = 0.f, dE = 0.f;
#pragma unroll
        for (int t = 0; t < 3; ++t) {
            float4 x = *reinterpret_cast<const float4*>(xb + t*256 + lane*4);
            xx += dot4(x, x);
            d0 += dot4(x, px[0][t]);
            d1 += dot4(x, px[1][t]);
            d2 += dot4(x, px[2][t]);
            d3 += dot4(x, px[3][t]);
            if constexpr (EDGE) { dS += dot4(x, vs[t]); dE += dot4(x, ve[t]); }
        }
        xx = wave_reduce_f(xx);
        d0 = wave_reduce_f(d0); d1 = wave_reduce_f(d1);
        d2 = wave_reduce_f(d2); d3 = wave_reduce_f(d3);
        if constexpr (EDGE) { dS = wave_reduce_f(dS); dE = wave_reduce_f(dE); }

        const int i = r & (NLL - 1);
        const int l = i >> 7, m = i & (LSEQ - 1);
        const bool valid = (l >= 1) && (l < lens_i - 1) && (m >= 1) && (m < lens_i - 1);
        const float xinv = 1.0f / fmaxf(sqrtf(xx), 1e-12f);
        if (valid) {
            const int lab = labels[r];
            float dd[4] = {d0, d1, d2, d3};
#pragma unroll
            for (int c = 0; c < NB; ++c) {
                float cs = dd[c] * xinv * pinv[c];
                if (c == lab) { accP[c] += expf(-ALPHA_C * (cs - MRG_C)); accC[c] += 1.0f; }
                else          { accN[c] += expf( ALPHA_C * (cs + MRG_C)); }
            }
        }
        if constexpr (EDGE) {
            const float xSl = dS + bSv, xEl = dE + bEv;
            const int ls = tlabS[r], le = tlabE[r];
            const float w = (ls >= 0) ? 1.0f : 0.0f;
            const float spS = fmaxf(xSl, 0.f) + log1pf(expf(-fabsf(xSl)));
            const float spE = fmaxf(xEl, 0.f) + log1pf(expf(-fabsf(xEl)));
            accBS += w * (spS - xSl * (float)ls);
            accBE += w * (spE - xEl * (float)le);
            if (lane == 0) {
                pS[r] = w / (1.f + expf(-xSl));
                pE[r] = w / (1.f + expf(-xEl));
            }
        }
    }

    if (lane == 0) {
        float* pp = partial + (size_t)wave * 14;
#pragma unroll
        for (int c = 0; c < NB; ++c) { pp[c] = accP[c]; pp[4+c] = accN[c]; pp[8+c] = accC[c]; }
        pp[12] = accBS; pp[13] = accBE;
    }
}

// Reduce partials (2 tables x 8192 waves x 14 slots) and emit the 4 scalar outputs.
__global__ __launch_bounds__(1024)
void finalize_k(const float* __restrict__ partE, const float* __restrict__ partS,
                float* __restrict__ out)
{
    __shared__ float g[112];   // [table][batch][slot] = 2*4*14
    const int tid = threadIdx.x, wave = tid >> 6, lane = tid & 63;
    for (int grp = wave; grp < 112; grp += 16) {
        const int tbl = grp / 56, rem = grp % 56, b = rem / 14, slot = rem % 14;
        const float* base = (tbl == 0 ? partE : partS) + (size_t)(b * 2048) * 14 + slot;
        float s = 0.f;
        for (int j = lane; j < 2048; j += 64) s += base[(size_t)j * 14];
        s = wave_reduce_f(s);
        if (lane == 0) g[grp] = s;
    }
    __syncthreads();
    if (tid == 0) {
        for (int t = 0; t < 2; ++t) {
            float tot = 0.f;
            for (int b = 0; b < NBATCH; ++b) {
                const float* G = g + t*56 + b*14;
                int nv = 0;
                for (int c = 0; c < NB; ++c) nv += (G[8+c] > 0.f) ? 1 : 0;
                const float nvf = (float)((nv > 1) ? nv : 1);
                float pos = 0.f, neg = 0.f;
                for (int c = 0; c < NB; ++c) { pos += log1pf(G[c]); neg += log1pf(G[4+c]); }
                tot += pos / nvf + neg * 0.25f;
            }
            out[t] = CLW_C * tot * 0.25f;
        }
        float bs = 0.f, be = 0.f;
        for (int b = 0; b < NBATCH; ++b) { bs += g[b*14 + 12]; be += g[b*14 + 13]; }
        out[2] = bs * (1.0f / 65536.0f);
        out[3] = be * (1.0f / 65536.0f);
    }
}

// Per (array, batch): exact k-th largest via 32-step binary search on uint bits
// (valid because all p >= 0), then pred = (p >= kth).
__global__ __launch_bounds__(1024)
void prune_k(const float* __restrict__ pS, const float* __restrict__ pE,
             const int* __restrict__ attn, float* __restrict__ out)
{
    const int a = blockIdx.x >> 2;   // 0 = S, 1 = E
    const int b = blockIdx.x & 3;
    const float* p = (a ? pE : pS) + (size_t)b * NLL;
    float* o = out + 4 + (size_t)a * (NBATCH * NLL) + (size_t)b * NLL;

    __shared__ unsigned sh[NLL];     // 64 KB
    __shared__ int csum[16];
    const int tid = threadIdx.x, wave = tid >> 6, lane = tid & 63;

    int asum = attn[b*LSEQ + lane] + attn[b*LSEQ + 64 + lane];
#pragma unroll
    for (int s = 1; s < 64; s <<= 1) asum += __shfl_xor(asum, s);
    const int mask_len = asum - 2;
    int k = (int)((float)mask_len * 0.3f);
    k = (k > 10) ? k : 10;
    const int ml2 = mask_len * mask_len;
    k = (k < ml2) ? k : ml2;

    for (int j = tid; j < NLL; j += 1024) sh[j] = __float_as_uint(p[j]);
    __syncthreads();

    unsigned lo = 0u, hi = 0xFFFFFFFFu;
    for (int it = 0; it < 32; ++it) {
        if (lo >= hi) break;                       // uniform across block
        const unsigned span = hi - lo;
        const unsigned mid = lo + (span >> 1) + (span & 1u);   // ceil midpoint, > lo
        int c = 0;
        for (int j = tid; j < NLL; j += 1024) c += (sh[j] >= mid) ? 1 : 0;
#pragma unroll
        for (int s = 1; s < 64; s <<= 1) c += __shfl_xor(c, s);
        if (lane == 0) csum[wave] = c;
        __syncthreads();
        int tot = 0;
#pragma unroll
        for (int w = 0; w < 16; ++w) tot += csum[w];
        if (tot >= k) lo = mid; else hi = mid - 1u;
        __syncthreads();
    }

    for (int j = tid; j < NLL; j += 1024) o[j] = (sh[j] >= lo) ? 1.0f : 0.0f;
}

extern "C" void kernel_launch(void* const* d_in, const int* in_sizes, int n_in,
                              void* d_out, int out_size, void* d_ws, size_t ws_size,
                              hipStream_t stream)
{
    const float* table_edge  = (const float*)d_in[0];
    const float* table_senti = (const float*)d_in[1];
    const int*   attn        = (const int*)d_in[2];
    const int*   tlabS       = (const int*)d_in[3];
    const int*   tlabE       = (const int*)d_in[4];
    const int*   lab_edge    = (const int*)d_in[5];
    const int*   lab_senti   = (const int*)d_in[6];
    const float* prox_edge   = (const float*)d_in[7];
    const float* prox_senti  = (const float*)d_in[8];
    const float* w_S         = (const float*)d_in[9];
    const float* b_S         = (const float*)d_in[10];
    const float* w_E         = (const float*)d_in[11];
    const float* b_E         = (const float*)d_in[12];

    float* out   = (float*)d_out;
    float* ws    = (float*)d_ws;
    float* pS    = ws;                      // 65536 floats
    float* pE    = ws + 65536;              // 65536 floats
    float* partE = ws + 131072;             // 8192*14 floats
    float* partS = partE + 8192*14;         // 8192*14 floats

    fused_pass<true><<<2048, 256, 0, stream>>>(table_edge, lab_edge, attn, prox_edge,
        w_S, b_S, w_E, b_E, tlabS, tlabE, pS, pE, partE);
    fused_pass<false><<<2048, 256, 0, stream>>>(table_senti, lab_senti, attn, prox_senti,
        nullptr, nullptr, nullptr, nullptr, nullptr, nullptr, nullptr, nullptr, partS);
    finalize_k<<<1, 1024, 0, stream>>>(partE, partS, out);
    prune_k<<<8, 1024, 0, stream>>>(pS, pE, attn, out);
}

// Round 2
// 172.550 us; speedup vs baseline: 1.3799x; 1.3799x over previous
//
#include <hip/hip_runtime.h>
#include <math.h>

#define LSEQ 128
#define NLL 16384      // L*L
#define NBATCH 4
#define DIM 768
#define NB 4
#define ALPHA_C 32.0f
#define MRG_C 0.05f
#define CLW_C 0.05f
#define BLKS_PER_BATCH 512   // 2048 blocks / 4 batches

__device__ __forceinline__ float wave_reduce_f(float v) {
#pragma unroll
    for (int s = 1; s < 64; s <<= 1) v += __shfl_xor(v, s);
    return v;
}

__device__ __forceinline__ float dot4(float4 a, float4 b) {
    return a.x*b.x + a.y*b.y + a.z*b.z + a.w*b.w;
}

// One wave handles 8 consecutive rows of 768 floats.
// Grid: 2048 blocks x 256 threads = 8192 waves * 8 rows = 65536 rows.
// Per-block LDS reduce -> partial[(batch*14+slot)*512 + blk_in_batch] (coalesced for finalize).
template<bool EDGE>
__global__ __launch_bounds__(256)
void fused_pass(const float* __restrict__ table,
                const int*   __restrict__ labels,
                const int*   __restrict__ attn,
                const float* __restrict__ prox,
                const float* __restrict__ wS, const float* __restrict__ bS,
                const float* __restrict__ wE, const float* __restrict__ bE,
                const int*   __restrict__ tlabS, const int* __restrict__ tlabE,
                float* __restrict__ pS, float* __restrict__ pE,
                float* __restrict__ partial /* [4*14*512] */)
{
    const int gtid = blockIdx.x * 256 + threadIdx.x;
    const int wave = gtid >> 6;
    const int wib  = (threadIdx.x >> 6);   // wave in block (0..3)
    const int lane = gtid & 63;
    const int row0 = wave * 8;
    const int b = row0 >> 14;   // 16384 rows per batch

    __shared__ float sacc[4][14];

    // lens[b] = sum(attention_mask[b])
    int lens_i = attn[b*LSEQ + lane] + attn[b*LSEQ + 64 + lane];
#pragma unroll
    for (int s = 1; s < 64; s <<= 1) lens_i += __shfl_xor(lens_i, s);

    // Preload proxies (this lane's slice) + proxy inverse norms
    float4 px[NB][3];
    float pinv[NB];
#pragma unroll
    for (int c = 0; c < NB; ++c) {
        float s2 = 0.f;
#pragma unroll
        for (int t = 0; t < 3; ++t) {
            px[c][t] = *reinterpret_cast<const float4*>(prox + c*DIM + t*256 + lane*4);
            s2 += dot4(px[c][t], px[c][t]);
        }
        s2 = wave_reduce_f(s2);
        pinv[c] = 1.0f / fmaxf(sqrtf(s2), 1e-12f);
    }
    float4 vs[3], ve[3];
    float bSv = 0.f, bEv = 0.f;
    if constexpr (EDGE) {
#pragma unroll
        for (int t = 0; t < 3; ++t) {
            vs[t] = *reinterpret_cast<const float4*>(wS + t*256 + lane*4);
            ve[t] = *reinterpret_cast<const float4*>(wE + t*256 + lane*4);
        }
        bSv = bS[0]; bEv = bE[0];
    }

    float accP[NB] = {0,0,0,0}, accN[NB] = {0,0,0,0}, accC[NB] = {0,0,0,0};
    float accBS = 0.f, accBE = 0.f;

    for (int rr = 0; rr < 8; ++rr) {
        const int r = row0 + rr;
        const float* xb = table + (size_t)r * DIM;
        float xx = 0.f, d0 = 0.f, d1 = 0.f, d2 = 0.f, d3 = 0.f, dS = 0.f, dE = 0.f;
#pragma unroll
        for (int t = 0; t < 3; ++t) {
            float4 x = *reinterpret_cast<const float4*>(xb + t*256 + lane*4);
            xx += dot4(x, x);
            d0 += dot4(x, px[0][t]);
            d1 += dot4(x, px[1][t]);
            d2 += dot4(x, px[2][t]);
            d3 += dot4(x, px[3][t]);
            if constexpr (EDGE) { dS += dot4(x, vs[t]); dE += dot4(x, ve[t]); }
        }
        xx = wave_reduce_f(xx);
        d0 = wave_reduce_f(d0); d1 = wave_reduce_f(d1);
        d2 = wave_reduce_f(d2); d3 = wave_reduce_f(d3);
        if constexpr (EDGE) { dS = wave_reduce_f(dS); dE = wave_reduce_f(dE); }

        const int i = r & (NLL - 1);
        const int l = i >> 7, m = i & (LSEQ - 1);
        const bool valid = (l >= 1) && (l < lens_i - 1) && (m >= 1) && (m < lens_i - 1);
        const float xinv = 1.0f / fmaxf(sqrtf(xx), 1e-12f);
        if (valid) {
            const int lab = labels[r];
            float dd[4] = {d0, d1, d2, d3};
#pragma unroll
            for (int c = 0; c < NB; ++c) {
                float cs = dd[c] * xinv * pinv[c];
                if (c == lab) { accP[c] += expf(-ALPHA_C * (cs - MRG_C)); accC[c] += 1.0f; }
                else          { accN[c] += expf( ALPHA_C * (cs + MRG_C)); }
            }
        }
        if constexpr (EDGE) {
            const float xSl = dS + bSv, xEl = dE + bEv;
            const int ls = tlabS[r], le = tlabE[r];
            const float w = (ls >= 0) ? 1.0f : 0.0f;
            const float spS = fmaxf(xSl, 0.f) + log1pf(expf(-fabsf(xSl)));
            const float spE = fmaxf(xEl, 0.f) + log1pf(expf(-fabsf(xEl)));
            accBS += w * (spS - xSl * (float)ls);
            accBE += w * (spE - xEl * (float)le);
            if (lane == 0) {
                pS[r] = w / (1.f + expf(-xSl));
                pE[r] = w / (1.f + expf(-xEl));
            }
        }
    }

    if (lane == 0) {
        float* sp = sacc[wib];
#pragma unroll
        for (int c = 0; c < NB; ++c) { sp[c] = accP[c]; sp[4+c] = accN[c]; sp[8+c] = accC[c]; }
        sp[12] = accBS; sp[13] = accBE;
    }
    __syncthreads();
    if (threadIdx.x < 14) {
        const float s = sacc[0][threadIdx.x] + sacc[1][threadIdx.x]
                      + sacc[2][threadIdx.x] + sacc[3][threadIdx.x];
        const int blk_in_batch = blockIdx.x & (BLKS_PER_BATCH - 1);
        partial[((size_t)(b * 14 + threadIdx.x)) * BLKS_PER_BATCH + blk_in_batch] = s;
    }
}

// Two blocks: block 0 = edge table (also emits BCE scalars), block 1 = senti.
// Each block reduces 56 groups of 512 contiguous floats (L2-resident).
__global__ __launch_bounds__(1024)
void finalize_k(const float* __restrict__ partE, const float* __restrict__ partS,
                float* __restrict__ out)
{
    const int tbl = blockIdx.x;
    const float* part = (tbl == 0) ? partE : partS;
    __shared__ float g[56];   // [batch][slot]
    const int tid = threadIdx.x, wave = tid >> 6, lane = tid & 63;
    for (int grp = wave; grp < 56; grp += 16) {
        const float* base = part + (size_t)grp * BLKS_PER_BATCH;
        float s = 0.f;
#pragma unroll
        for (int j = lane; j < BLKS_PER_BATCH; j += 64) s += base[j];
        s = wave_reduce_f(s);
        if (lane == 0) g[grp] = s;
    }
    __syncthreads();
    if (tid == 0) {
        float tot = 0.f;
        for (int b = 0; b < NBATCH; ++b) {
            const float* G = g + b * 14;
            int nv = 0;
            for (int c = 0; c < NB; ++c) nv += (G[8+c] > 0.f) ? 1 : 0;
            const float nvf = (float)((nv > 1) ? nv : 1);
            float pos = 0.f, neg = 0.f;
            for (int c = 0; c < NB; ++c) { pos += log1pf(G[c]); neg += log1pf(G[4+c]); }
            tot += pos / nvf + neg * 0.25f;
        }
        out[tbl] = CLW_C * tot * 0.25f;
        if (tbl == 0) {
            float bs = 0.f, be = 0.f;
            for (int b = 0; b < NBATCH; ++b) { bs += g[b*14 + 12]; be += g[b*14 + 13]; }
            out[2] = bs * (1.0f / 65536.0f);
            out[3] = be * (1.0f / 65536.0f);
        }
    }
}

// Per (array, batch): exact k-th largest via 32-step binary search on uint bits
// (valid because all p >= 0), then pred = (p >= kth).
__global__ __launch_bounds__(1024)
void prune_k(const float* __restrict__ pS, const float* __restrict__ pE,
             const int* __restrict__ attn, float* __restrict__ out)
{
    const int a = blockIdx.x >> 2;   // 0 = S, 1 = E
    const int b = blockIdx.x & 3;
    const float* p = (a ? pE : pS) + (size_t)b * NLL;
    float* o = out + 4 + (size_t)a * (NBATCH * NLL) + (size_t)b * NLL;

    __shared__ unsigned sh[NLL];     // 64 KB
    __shared__ int csum[16];
    const int tid = threadIdx.x, wave = tid >> 6, lane = tid & 63;

    int asum = attn[b*LSEQ + lane] + attn[b*LSEQ + 64 + lane];
#pragma unroll
    for (int s = 1; s < 64; s <<= 1) asum += __shfl_xor(asum, s);
    const int mask_len = asum - 2;
    int k = (int)((float)mask_len * 0.3f);
    k = (k > 10) ? k : 10;
    const int ml2 = mask_len * mask_len;
    k = (k < ml2) ? k : ml2;

    for (int j = tid; j < NLL; j += 1024) sh[j] = __float_as_uint(p[j]);
    __syncthreads();

    unsigned lo = 0u, hi = 0xFFFFFFFFu;
    for (int it = 0; it < 32; ++it) {
        if (lo >= hi) break;                       // uniform across block
        const unsigned span = hi - lo;
        const unsigned mid = lo + (span >> 1) + (span & 1u);   // ceil midpoint, > lo
        int c = 0;
        for (int j = tid; j < NLL; j += 1024) c += (sh[j] >= mid) ? 1 : 0;
#pragma unroll
        for (int s = 1; s < 64; s <<= 1) c += __shfl_xor(c, s);
        if (lane == 0) csum[wave] = c;
        __syncthreads();
        int tot = 0;
#pragma unroll
        for (int w = 0; w < 16; ++w) tot += csum[w];
        if (tot >= k) lo = mid; else hi = mid - 1u;
        __syncthreads();
    }

    for (int j = tid; j < NLL; j += 1024) o[j] = (sh[j] >= lo) ? 1.0f : 0.0f;
}

extern "C" void kernel_launch(void* const* d_in, const int* in_sizes, int n_in,
                              void* d_out, int out_size, void* d_ws, size_t ws_size,
                              hipStream_t stream)
{
    const float* table_edge  = (const float*)d_in[0];
    const float* table_senti = (const float*)d_in[1];
    const int*   attn        = (const int*)d_in[2];
    const int*   tlabS       = (const int*)d_in[3];
    const int*   tlabE       = (const int*)d_in[4];
    const int*   lab_edge    = (const int*)d_in[5];
    const int*   lab_senti   = (const int*)d_in[6];
    const float* prox_edge   = (const float*)d_in[7];
    const float* prox_senti  = (const float*)d_in[8];
    const float* w_S         = (const float*)d_in[9];
    const float* b_S         = (const float*)d_in[10];
    const float* w_E         = (const float*)d_in[11];
    const float* b_E         = (const float*)d_in[12];

    float* out   = (float*)d_out;
    float* ws    = (float*)d_ws;
    float* pS    = ws;                      // 65536 floats
    float* pE    = ws + 65536;              // 65536 floats
    float* partE = ws + 131072;             // 4*14*512 = 28672 floats
    float* partS = partE + 28672;           // 28672 floats

    fused_pass<true><<<2048, 256, 0, stream>>>(table_edge, lab_edge, attn, prox_edge,
        w_S, b_S, w_E, b_E, tlabS, tlabE, pS, pE, partE);
    fused_pass<false><<<2048, 256, 0, stream>>>(table_senti, lab_senti, attn, prox_senti,
        nullptr, nullptr, nullptr, nullptr, nullptr, nullptr, nullptr, nullptr, partS);
    finalize_k<<<2, 1024, 0, stream>>>(partE, partS, out);
    prune_k<<<8, 1024, 0, stream>>>(pS, pE, attn, out);
}

// Round 3
// 172.325 us; speedup vs baseline: 1.3817x; 1.0013x over previous
//
#include <hip/hip_runtime.h>
#include <math.h>

#define LSEQ 128
#define NLL 16384      // L*L
#define NBATCH 4
#define DIM 768
#define NB 4
#define ALPHA_C 32.0f
#define MRG_C 0.05f
#define CLW_C 0.05f
#define BLKS_PER_BATCH 512   // 2048 blocks / 4 batches

__device__ __forceinline__ float wave_reduce_f(float v) {
#pragma unroll
    for (int s = 1; s < 64; s <<= 1) v += __shfl_xor(v, s);
    return v;
}

__device__ __forceinline__ float dot4(float4 a, float4 b) {
    return a.x*b.x + a.y*b.y + a.z*b.z + a.w*b.w;
}

// One wave handles 8 consecutive rows of 768 floats.
// Grid: 2048 blocks x 256 threads = 8192 waves * 8 rows = 65536 rows.
// __launch_bounds__(256,2): VGPR budget 256/wave so the EDGE variant's
// ~120-VGPR working set (px 48 + vs/ve 24 + accs) stays in registers (no spill).
template<bool EDGE>
__global__ __launch_bounds__(256, 2)
void fused_pass(const float* __restrict__ table,
                const int*   __restrict__ labels,
                const int*   __restrict__ attn,
                const float* __restrict__ prox,
                const float* __restrict__ wS, const float* __restrict__ bS,
                const float* __restrict__ wE, const float* __restrict__ bE,
                const int*   __restrict__ tlabS, const int* __restrict__ tlabE,
                float* __restrict__ pS, float* __restrict__ pE,
                float* __restrict__ partial /* [4*14*512] */)
{
    const int gtid = blockIdx.x * 256 + threadIdx.x;
    const int wave = gtid >> 6;
    const int wib  = (threadIdx.x >> 6);   // wave in block (0..3)
    const int lane = gtid & 63;
    const int row0 = wave * 8;
    const int b = row0 >> 14;   // 16384 rows per batch

    __shared__ float sacc[4][14];

    // lens[b] = sum(attention_mask[b])
    int lens_i = attn[b*LSEQ + lane] + attn[b*LSEQ + 64 + lane];
#pragma unroll
    for (int s = 1; s < 64; s <<= 1) lens_i += __shfl_xor(lens_i, s);

    // Preload proxies (this lane's slice) + proxy inverse norms
    float4 px[NB][3];
    float pinv[NB];
#pragma unroll
    for (int c = 0; c < NB; ++c) {
        float s2 = 0.f;
#pragma unroll
        for (int t = 0; t < 3; ++t) {
            px[c][t] = *reinterpret_cast<const float4*>(prox + c*DIM + t*256 + lane*4);
            s2 += dot4(px[c][t], px[c][t]);
        }
        s2 = wave_reduce_f(s2);
        pinv[c] = 1.0f / fmaxf(sqrtf(s2), 1e-12f);
    }
    float4 vs[3], ve[3];
    float bSv = 0.f, bEv = 0.f;
    if constexpr (EDGE) {
#pragma unroll
        for (int t = 0; t < 3; ++t) {
            vs[t] = *reinterpret_cast<const float4*>(wS + t*256 + lane*4);
            ve[t] = *reinterpret_cast<const float4*>(wE + t*256 + lane*4);
        }
        bSv = bS[0]; bEv = bE[0];
    }

    float accP[NB] = {0,0,0,0}, accN[NB] = {0,0,0,0}, accC[NB] = {0,0,0,0};
    float accBS = 0.f, accBE = 0.f;

#pragma unroll 1
    for (int rr = 0; rr < 8; ++rr) {
        const int r = row0 + rr;
        const float* xb = table + (size_t)r * DIM;
        float xx = 0.f, d0 = 0.f, d1 = 0.f, d2 = 0.f, d3 = 0.f, dS = 0.f, dE = 0.f;
#pragma unroll
        for (int t = 0; t < 3; ++t) {
            float4 x = *reinterpret_cast<const float4*>(xb + t*256 + lane*4);
            xx += dot4(x, x);
            d0 += dot4(x, px[0][t]);
            d1 += dot4(x, px[1][t]);
            d2 += dot4(x, px[2][t]);
            d3 += dot4(x, px[3][t]);
            if constexpr (EDGE) { dS += dot4(x, vs[t]); dE += dot4(x, ve[t]); }
        }
        xx = wave_reduce_f(xx);
        d0 = wave_reduce_f(d0); d1 = wave_reduce_f(d1);
        d2 = wave_reduce_f(d2); d3 = wave_reduce_f(d3);
        if constexpr (EDGE) { dS = wave_reduce_f(dS); dE = wave_reduce_f(dE); }

        const int i = r & (NLL - 1);
        const int l = i >> 7, m = i & (LSEQ - 1);
        const bool valid = (l >= 1) && (l < lens_i - 1) && (m >= 1) && (m < lens_i - 1);
        const float xinv = 1.0f / fmaxf(sqrtf(xx), 1e-12f);
        if (valid) {
            const int lab = labels[r];
            float dd[4] = {d0, d1, d2, d3};
#pragma unroll
            for (int c = 0; c < NB; ++c) {
                float cs = dd[c] * xinv * pinv[c];
                if (c == lab) { accP[c] += expf(-ALPHA_C * (cs - MRG_C)); accC[c] += 1.0f; }
                else          { accN[c] += expf( ALPHA_C * (cs + MRG_C)); }
            }
        }
        if constexpr (EDGE) {
            const float xSl = dS + bSv, xEl = dE + bEv;
            const int ls = tlabS[r], le = tlabE[r];
            const float w = (ls >= 0) ? 1.0f : 0.0f;
            const float spS = fmaxf(xSl, 0.f) + log1pf(expf(-fabsf(xSl)));
            const float spE = fmaxf(xEl, 0.f) + log1pf(expf(-fabsf(xEl)));
            accBS += w * (spS - xSl * (float)ls);
            accBE += w * (spE - xEl * (float)le);
            if (lane == 0) {
                pS[r] = w / (1.f + expf(-xSl));
                pE[r] = w / (1.f + expf(-xEl));
            }
        }
    }

    if (lane == 0) {
        float* sp = sacc[wib];
#pragma unroll
        for (int c = 0; c < NB; ++c) { sp[c] = accP[c]; sp[4+c] = accN[c]; sp[8+c] = accC[c]; }
        sp[12] = accBS; sp[13] = accBE;
    }
    __syncthreads();
    if (threadIdx.x < 14) {
        const float s = sacc[0][threadIdx.x] + sacc[1][threadIdx.x]
                      + sacc[2][threadIdx.x] + sacc[3][threadIdx.x];
        const int blk_in_batch = blockIdx.x & (BLKS_PER_BATCH - 1);
        partial[((size_t)(b * 14 + threadIdx.x)) * BLKS_PER_BATCH + blk_in_batch] = s;
    }
}

// Two blocks: block 0 = edge table (also emits BCE scalars), block 1 = senti.
// Each block reduces 56 groups of 512 contiguous floats (L2-resident).
__global__ __launch_bounds__(1024)
void finalize_k(const float* __restrict__ partE, const float* __restrict__ partS,
                float* __restrict__ out)
{
    const int tbl = blockIdx.x;
    const float* part = (tbl == 0) ? partE : partS;
    __shared__ float g[56];   // [batch][slot]
    const int tid = threadIdx.x, wave = tid >> 6, lane = tid & 63;
    for (int grp = wave; grp < 56; grp += 16) {
        const float* base = part + (size_t)grp * BLKS_PER_BATCH;
        float s = 0.f;
#pragma unroll
        for (int j = lane; j < BLKS_PER_BATCH; j += 64) s += base[j];
        s = wave_reduce_f(s);
        if (lane == 0) g[grp] = s;
    }
    __syncthreads();
    if (tid == 0) {
        float tot = 0.f;
        for (int b = 0; b < NBATCH; ++b) {
            const float* G = g + b * 14;
            int nv = 0;
            for (int c = 0; c < NB; ++c) nv += (G[8+c] > 0.f) ? 1 : 0;
            const float nvf = (float)((nv > 1) ? nv : 1);
            float pos = 0.f, neg = 0.f;
            for (int c = 0; c < NB; ++c) { pos += log1pf(G[c]); neg += log1pf(G[4+c]); }
            tot += pos / nvf + neg * 0.25f;
        }
        out[tbl] = CLW_C * tot * 0.25f;
        if (tbl == 0) {
            float bs = 0.f, be = 0.f;
            for (int b = 0; b < NBATCH; ++b) { bs += g[b*14 + 12]; be += g[b*14 + 13]; }
            out[2] = bs * (1.0f / 65536.0f);
            out[3] = be * (1.0f / 65536.0f);
        }
    }
}

// Per (array, batch): exact k-th largest via 32-step binary search on uint bits
// (valid because all p >= 0), then pred = (p >= kth).
__global__ __launch_bounds__(1024)
void prune_k(const float* __restrict__ pS, const float* __restrict__ pE,
             const int* __restrict__ attn, float* __restrict__ out)
{
    const int a = blockIdx.x >> 2;   // 0 = S, 1 = E
    const int b = blockIdx.x & 3;
    const float* p = (a ? pE : pS) + (size_t)b * NLL;
    float* o = out + 4 + (size_t)a * (NBATCH * NLL) + (size_t)b * NLL;

    __shared__ unsigned sh[NLL];     // 64 KB
    __shared__ int csum[16];
    const int tid = threadIdx.x, wave = tid >> 6, lane = tid & 63;

    int asum = attn[b*LSEQ + lane] + attn[b*LSEQ + 64 + lane];
#pragma unroll
    for (int s = 1; s < 64; s <<= 1) asum += __shfl_xor(asum, s);
    const int mask_len = asum - 2;
    int k = (int)((float)mask_len * 0.3f);
    k = (k > 10) ? k : 10;
    const int ml2 = mask_len * mask_len;
    k = (k < ml2) ? k : ml2;

    for (int j = tid; j < NLL; j += 1024) sh[j] = __float_as_uint(p[j]);
    __syncthreads();

    unsigned lo = 0u, hi = 0xFFFFFFFFu;
    for (int it = 0; it < 32; ++it) {
        if (lo >= hi) break;                       // uniform across block
        const unsigned span = hi - lo;
        const unsigned mid = lo + (span >> 1) + (span & 1u);   // ceil midpoint, > lo
        int c = 0;
        for (int j = tid; j < NLL; j += 1024) c += (sh[j] >= mid) ? 1 : 0;
#pragma unroll
        for (int s = 1; s < 64; s <<= 1) c += __shfl_xor(c, s);
        if (lane == 0) csum[wave] = c;
        __syncthreads();
        int tot = 0;
#pragma unroll
        for (int w = 0; w < 16; ++w) tot += csum[w];
        if (tot >= k) lo = mid; else hi = mid - 1u;
        __syncthreads();
    }

    for (int j = tid; j < NLL; j += 1024) o[j] = (sh[j] >= lo) ? 1.0f : 0.0f;
}

extern "C" void kernel_launch(void* const* d_in, const int* in_sizes, int n_in,
                              void* d_out, int out_size, void* d_ws, size_t ws_size,
                              hipStream_t stream)
{
    const float* table_edge  = (const float*)d_in[0];
    const float* table_senti = (const float*)d_in[1];
    const int*   attn        = (const int*)d_in[2];
    const int*   tlabS       = (const int*)d_in[3];
    const int*   tlabE       = (const int*)d_in[4];
    const int*   lab_edge    = (const int*)d_in[5];
    const int*   lab_senti   = (const int*)d_in[6];
    const float* prox_edge   = (const float*)d_in[7];
    const float* prox_senti  = (const float*)d_in[8];
    const float* w_S         = (const float*)d_in[9];
    const float* b_S         = (const float*)d_in[10];
    const float* w_E         = (const float*)d_in[11];
    const float* b_E         = (const float*)d_in[12];

    float* out   = (float*)d_out;
    float* ws    = (float*)d_ws;
    float* pS    = ws;                      // 65536 floats
    float* pE    = ws + 65536;              // 65536 floats
    float* partE = ws + 131072;             // 4*14*512 = 28672 floats
    float* partS = partE + 28672;           // 28672 floats

    fused_pass<true><<<2048, 256, 0, stream>>>(table_edge, lab_edge, attn, prox_edge,
        w_S, b_S, w_E, b_E, tlabS, tlabE, pS, pE, partE);
    fused_pass<false><<<2048, 256, 0, stream>>>(table_senti, lab_senti, attn, prox_senti,
        nullptr, nullptr, nullptr, nullptr, nullptr, nullptr, nullptr, nullptr, partS);
    finalize_k<<<2, 1024, 0, stream>>>(partE, partS, out);
    prune_k<<<8, 1024, 0, stream>>>(pS, pE, attn, out);
}

// Round 4
// 110.680 us; speedup vs baseline: 2.1512x; 1.5570x over previous
//
#include <hip/hip_runtime.h>
#include <math.h>

#define LSEQ 128
#define NLL 16384      // L*L
#define NBATCH 4
#define DIM 768
#define NB 4
#define ALPHA_C 32.0f
#define MRG_C 0.05f
#define CLW_C 0.05f
#define BPB 256        // blocks per batch per table (1024/4)
#define KSTEPS 48      // 768 floats / (4 lanes * 4 floats)

__device__ __forceinline__ float wave_reduce_f(float v) {
#pragma unroll
    for (int s = 1; s < 64; s <<= 1) v += __shfl_xor(v, s);
    return v;
}

__device__ __forceinline__ float dot4(float4 a, float4 b) {
    return a.x*b.x + a.y*b.y + a.z*b.z + a.w*b.w;
}

// 4 lanes per row, 16 rows per wave, 64 rows per 256-thread block.
// Weights broadcast from LDS; no per-row cross-lane reductions.
template<bool EDGE>
__device__ __forceinline__ void kloop(const float* __restrict__ rowp,
                                      const float* __restrict__ wlds, int sub,
                                      float& aXX, float& a0, float& a1, float& a2, float& a3,
                                      float& aS, float& aE)
{
#pragma unroll 4
    for (int k = 0; k < KSTEPS; ++k) {
        const int off = k*16 + sub*4;
        const float4 x = *reinterpret_cast<const float4*>(rowp + off);
        aXX += dot4(x, x);
        a0 += dot4(x, *reinterpret_cast<const float4*>(&wlds[0*DIM + off]));
        a1 += dot4(x, *reinterpret_cast<const float4*>(&wlds[1*DIM + off]));
        a2 += dot4(x, *reinterpret_cast<const float4*>(&wlds[2*DIM + off]));
        a3 += dot4(x, *reinterpret_cast<const float4*>(&wlds[3*DIM + off]));
        if constexpr (EDGE) {
            aS += dot4(x, *reinterpret_cast<const float4*>(&wlds[4*DIM + off]));
            aE += dot4(x, *reinterpret_cast<const float4*>(&wlds[5*DIM + off]));
        }
    }
}

// grid 2048: blocks [0,1024) = edge table, [1024,2048) = senti table.
__global__ __launch_bounds__(256)
void fused_pass(const float* __restrict__ tabE, const float* __restrict__ tabS,
                const int* __restrict__ labE, const int* __restrict__ labSen,
                const int* __restrict__ attn,
                const float* __restrict__ proxE, const float* __restrict__ proxSen,
                const float* __restrict__ wS, const float* __restrict__ bS,
                const float* __restrict__ wE, const float* __restrict__ bE,
                const int* __restrict__ tlabS, const int* __restrict__ tlabE,
                float* __restrict__ pS, float* __restrict__ pE,
                float* __restrict__ partE, float* __restrict__ partSen)
{
    __shared__ float wlds[6*DIM];   // up to 6 weight vectors (4 proxies + wS + wE)
    __shared__ float red[7*64];     // per-row reduced dots: [slot][row]

    const int tid = threadIdx.x, wib = tid >> 6, lane = tid & 63;
    const int tbl = blockIdx.x >> 10;
    const int g = blockIdx.x & 1023;
    const int row0 = g << 6;        // 64 rows per block (within this table)
    const int b = g >> 8;           // batch
    const bool EDGE = (tbl == 0);

    const float* table = EDGE ? tabE : tabS;
    const float* prox  = EDGE ? proxE : proxSen;
    const int NW = EDGE ? 6 : 4;

    // cooperative weight load into LDS
    for (int i2 = tid; i2 < NW*192; i2 += 256) {
        const int v = i2 / 192, e = (i2 % 192) * 4;
        const float* src = (v < 4) ? (prox + v*DIM + e) : ((v == 4) ? (wS + e) : (wE + e));
        *reinterpret_cast<float4*>(&wlds[v*DIM + e]) = *reinterpret_cast<const float4*>(src);
    }
    __syncthreads();

    const int rgrp = lane >> 2, sub = lane & 3;
    const int myrow = row0 + wib*16 + rgrp;
    const float* rowp = table + (size_t)myrow * DIM;

    float aXX=0.f, a0=0.f, a1=0.f, a2=0.f, a3=0.f, aS=0.f, aE=0.f;
    if (EDGE) kloop<true >(rowp, wlds, sub, aXX, a0, a1, a2, a3, aS, aE);
    else      kloop<false>(rowp, wlds, sub, aXX, a0, a1, a2, a3, aS, aE);

    // reduce across the 4-lane group (2 stages)
#pragma unroll
    for (int s = 1; s < 4; s <<= 1) {
        aXX += __shfl_xor(aXX, s); a0 += __shfl_xor(a0, s); a1 += __shfl_xor(a1, s);
        a2  += __shfl_xor(a2, s);  a3 += __shfl_xor(a3, s);
        aS  += __shfl_xor(aS, s);  aE += __shfl_xor(aE, s);
    }
    if (sub == 0) {
        const int rr = wib*16 + rgrp;
        red[0*64+rr]=aXX; red[1*64+rr]=a0; red[2*64+rr]=a1; red[3*64+rr]=a2;
        red[4*64+rr]=a3;  red[5*64+rr]=aS; red[6*64+rr]=aE;
    }
    __syncthreads();
    if (wib != 0) return;

    // ---------- wave 0 epilogue: 64 rows lane-parallel ----------
    int lens_i = attn[b*LSEQ + lane] + attn[b*LSEQ + 64 + lane];
#pragma unroll
    for (int s = 1; s < 64; s <<= 1) lens_i += __shfl_xor(lens_i, s);

    float pinv[NB];
#pragma unroll
    for (int c = 0; c < NB; ++c) {
        float s2 = 0.f;
#pragma unroll
        for (int t = 0; t < 12; ++t) { const float w = wlds[c*DIM + t*64 + lane]; s2 += w*w; }
        s2 = wave_reduce_f(s2);
        pinv[c] = 1.0f / fmaxf(sqrtf(s2), 1e-12f);
    }

    const int r = row0 + lane;      // row within this table [0,65536)
    const float xx = red[lane];
    float dd[NB] = { red[64+lane], red[128+lane], red[192+lane], red[256+lane] };
    const float xinv = 1.0f / fmaxf(sqrtf(xx), 1e-12f);
    const int i = r & (NLL - 1);
    const int l = i >> 7, m = i & (LSEQ - 1);
    const bool valid = (l >= 1) && (l < lens_i - 1) && (m >= 1) && (m < lens_i - 1);
    const int lab = (EDGE ? labE : labSen)[r];

    float Pa[NB] = {0,0,0,0}, Na[NB] = {0,0,0,0}, Ca[NB] = {0,0,0,0};
    if (valid) {
#pragma unroll
        for (int c = 0; c < NB; ++c) {
            const float cs = dd[c] * xinv * pinv[c];
            if (lab == c) { Pa[c] = expf(-ALPHA_C * (cs - MRG_C)); Ca[c] = 1.f; }
            else          { Na[c] = expf( ALPHA_C * (cs + MRG_C)); }
        }
    }
    float sBS = 0.f, sBE = 0.f;
    if (EDGE) {
        const float dS = red[320+lane], dE = red[384+lane];
        const float xSl = dS + bS[0], xEl = dE + bE[0];
        const int ls = tlabS[r], le = tlabE[r];
        const float w = (ls >= 0) ? 1.f : 0.f;
        const float spS = fmaxf(xSl, 0.f) + log1pf(expf(-fabsf(xSl)));
        const float spE = fmaxf(xEl, 0.f) + log1pf(expf(-fabsf(xEl)));
        sBS = w * (spS - xSl * (float)ls);
        sBE = w * (spE - xEl * (float)le);
        pS[r] = w / (1.f + expf(-xSl));
        pE[r] = w / (1.f + expf(-xEl));
    }

#pragma unroll
    for (int c = 0; c < NB; ++c) {
        Pa[c] = wave_reduce_f(Pa[c]); Na[c] = wave_reduce_f(Na[c]); Ca[c] = wave_reduce_f(Ca[c]);
    }
    sBS = wave_reduce_f(sBS); sBE = wave_reduce_f(sBE);

    if (lane == 0) {
        float* pp = EDGE ? partE : partSen;
        const int blk = g & (BPB - 1);
        const int base = b * 14;
#pragma unroll
        for (int c = 0; c < NB; ++c) {
            pp[(base + c)     * BPB + blk] = Pa[c];
            pp[(base + 4 + c) * BPB + blk] = Na[c];
            pp[(base + 8 + c) * BPB + blk] = Ca[c];
        }
        pp[(base + 12) * BPB + blk] = sBS;
        pp[(base + 13) * BPB + blk] = sBE;
    }
}

// 10 blocks: 0-7 = prune (exact k-th largest), 8-9 = finalize (scalar outputs).
__global__ __launch_bounds__(1024)
void tail_k(const float* __restrict__ pS, const float* __restrict__ pE,
            const int* __restrict__ attn,
            const float* __restrict__ partE, const float* __restrict__ partS,
            float* __restrict__ out)
{
    __shared__ unsigned sh[NLL];     // 64 KB (prune path)
    __shared__ int csum[16];
    __shared__ float gg[56];
    const int tid = threadIdx.x, wave = tid >> 6, lane = tid & 63;

    if (blockIdx.x >= 8) {
        const int tbl = blockIdx.x - 8;
        const float* part = (tbl == 0) ? partE : partS;
        for (int grp = wave; grp < 56; grp += 16) {
            float s = 0.f;
#pragma unroll
            for (int j = lane; j < BPB; j += 64) s += part[grp*BPB + j];
            s = wave_reduce_f(s);
            if (lane == 0) gg[grp] = s;
        }
        __syncthreads();
        if (tid == 0) {
            float tot = 0.f;
            for (int b = 0; b < NBATCH; ++b) {
                const float* G = gg + b * 14;
                int nv = 0;
                for (int c = 0; c < NB; ++c) nv += (G[8+c] > 0.f) ? 1 : 0;
                const float nvf = (float)((nv > 1) ? nv : 1);
                float pos = 0.f, neg = 0.f;
                for (int c = 0; c < NB; ++c) { pos += log1pf(G[c]); neg += log1pf(G[4+c]); }
                tot += pos / nvf + neg * 0.25f;
            }
            out[tbl] = CLW_C * tot * 0.25f;
            if (tbl == 0) {
                float bs = 0.f, be = 0.f;
                for (int b = 0; b < NBATCH; ++b) { bs += gg[b*14 + 12]; be += gg[b*14 + 13]; }
                out[2] = bs * (1.0f / 65536.0f);
                out[3] = be * (1.0f / 65536.0f);
            }
        }
        return;
    }

    const int a = blockIdx.x >> 2;   // 0 = S, 1 = E
    const int b = blockIdx.x & 3;
    const float* p = (a ? pE : pS) + (size_t)b * NLL;
    float* o = out + 4 + (size_t)a * (NBATCH * NLL) + (size_t)b * NLL;

    int asum = attn[b*LSEQ + lane] + attn[b*LSEQ + 64 + lane];
#pragma unroll
    for (int s = 1; s < 64; s <<= 1) asum += __shfl_xor(asum, s);
    const int mask_len = asum - 2;
    int k = (int)((float)mask_len * 0.3f);
    k = (k > 10) ? k : 10;
    const int ml2 = mask_len * mask_len;
    k = (k < ml2) ? k : ml2;

    for (int j = tid; j < NLL; j += 1024) sh[j] = __float_as_uint(p[j]);
    __syncthreads();

    unsigned lo = 0u, hi = 0xFFFFFFFFu;
    for (int it = 0; it < 32; ++it) {
        if (lo >= hi) break;                       // uniform across block
        const unsigned span = hi - lo;
        const unsigned mid = lo + (span >> 1) + (span & 1u);   // ceil midpoint, > lo
        int c = 0;
        for (int j = tid; j < NLL; j += 1024) c += (sh[j] >= mid) ? 1 : 0;
#pragma unroll
        for (int s = 1; s < 64; s <<= 1) c += __shfl_xor(c, s);
        if (lane == 0) csum[wave] = c;
        __syncthreads();
        int tot = 0;
#pragma unroll
        for (int w = 0; w < 16; ++w) tot += csum[w];
        if (tot >= k) lo = mid; else hi = mid - 1u;
        __syncthreads();
    }

    for (int j = tid; j < NLL; j += 1024) o[j] = (sh[j] >= lo) ? 1.0f : 0.0f;
}

extern "C" void kernel_launch(void* const* d_in, const int* in_sizes, int n_in,
                              void* d_out, int out_size, void* d_ws, size_t ws_size,
                              hipStream_t stream)
{
    const float* table_edge  = (const float*)d_in[0];
    const float* table_senti = (const float*)d_in[1];
    const int*   attn        = (const int*)d_in[2];
    const int*   tlabS       = (const int*)d_in[3];
    const int*   tlabE       = (const int*)d_in[4];
    const int*   lab_edge    = (const int*)d_in[5];
    const int*   lab_senti   = (const int*)d_in[6];
    const float* prox_edge   = (const float*)d_in[7];
    const float* prox_senti  = (const float*)d_in[8];
    const float* w_S         = (const float*)d_in[9];
    const float* b_S         = (const float*)d_in[10];
    const float* w_E         = (const float*)d_in[11];
    const float* b_E         = (const float*)d_in[12];

    float* out   = (float*)d_out;
    float* ws    = (float*)d_ws;
    float* pS    = ws;                      // 65536
    float* pE    = ws + 65536;              // 65536
    float* partE = ws + 131072;             // 4*14*256 = 14336
    float* partS = partE + 14336;           // 14336

    fused_pass<<<2048, 256, 0, stream>>>(table_edge, table_senti,
        lab_edge, lab_senti, attn, prox_edge, prox_senti,
        w_S, b_S, w_E, b_E, tlabS, tlabE, pS, pE, partE, partS);
    tail_k<<<10, 1024, 0, stream>>>(pS, pE, attn, partE, partS, out);
}

// Round 5
// 109.404 us; speedup vs baseline: 2.1763x; 1.0117x over previous
//
#include <hip/hip_runtime.h>
#include <math.h>

#define LSEQ 128
#define NLL 16384      // L*L
#define NBATCH 4
#define DIM 768
#define NB 4
#define ALPHA_C 32.0f
#define MRG_C 0.05f
#define CLW_C 0.05f
#define BPB 256        // blocks per batch per table (1024/4)
#define KS 24          // 768 floats / (8 lanes * 4 floats)

__device__ __forceinline__ float wave_reduce_f(float v) {
#pragma unroll
    for (int s = 1; s < 64; s <<= 1) v += __shfl_xor(v, s);
    return v;
}

__device__ __forceinline__ float dot4(float4 a, float4 b) {
    return a.x*b.x + a.y*b.y + a.z*b.z + a.w*b.w;
}

// 8 lanes per row (128B segments), 2 rows per lane-group -> 16 rows/wave,
// 64 rows per 256-thread block. Each weight ds_read feeds 2 rows.
template<bool EDGE>
__device__ __forceinline__ void kloop2(const float* __restrict__ rp0,
                                       const float* __restrict__ rp1,
                                       const float* __restrict__ wlds, int sub,
                                       float& xx0, float& d00, float& d01, float& d02, float& d03,
                                       float& dS0, float& dE0,
                                       float& xx1, float& d10, float& d11, float& d12, float& d13,
                                       float& dS1, float& dE1)
{
#pragma unroll 4
    for (int k = 0; k < KS; ++k) {
        const int off = k*32 + sub*4;
        const float4 x0 = *reinterpret_cast<const float4*>(rp0 + off);
        const float4 x1 = *reinterpret_cast<const float4*>(rp1 + off);
        const float4 w0 = *reinterpret_cast<const float4*>(&wlds[0*DIM + off]);
        const float4 w1 = *reinterpret_cast<const float4*>(&wlds[1*DIM + off]);
        const float4 w2 = *reinterpret_cast<const float4*>(&wlds[2*DIM + off]);
        const float4 w3 = *reinterpret_cast<const float4*>(&wlds[3*DIM + off]);
        xx0 += dot4(x0,x0); d00 += dot4(x0,w0); d01 += dot4(x0,w1); d02 += dot4(x0,w2); d03 += dot4(x0,w3);
        xx1 += dot4(x1,x1); d10 += dot4(x1,w0); d11 += dot4(x1,w1); d12 += dot4(x1,w2); d13 += dot4(x1,w3);
        if constexpr (EDGE) {
            const float4 w4 = *reinterpret_cast<const float4*>(&wlds[4*DIM + off]);
            const float4 w5 = *reinterpret_cast<const float4*>(&wlds[5*DIM + off]);
            dS0 += dot4(x0,w4); dE0 += dot4(x0,w5);
            dS1 += dot4(x1,w4); dE1 += dot4(x1,w5);
        }
    }
}

// grid 2048: blocks [0,1024) = edge table, [1024,2048) = senti table.
__global__ __launch_bounds__(256)
void fused_pass(const float* __restrict__ tabE, const float* __restrict__ tabS,
                const int* __restrict__ labE, const int* __restrict__ labSen,
                const int* __restrict__ attn,
                const float* __restrict__ proxE, const float* __restrict__ proxSen,
                const float* __restrict__ wS, const float* __restrict__ bS,
                const float* __restrict__ wE, const float* __restrict__ bE,
                const int* __restrict__ tlabS, const int* __restrict__ tlabE,
                float* __restrict__ pS, float* __restrict__ pE,
                float* __restrict__ partE, float* __restrict__ partSen)
{
    __shared__ float wlds[6*DIM];   // 18432 B
    __shared__ float red[7*64];     // 1792 B  (total 20224 B -> 8 blocks/CU)

    const int tid = threadIdx.x, wib = tid >> 6, lane = tid & 63;
    const int tbl = blockIdx.x >> 10;
    const int g = blockIdx.x & 1023;
    const int row0 = g << 6;        // 64 rows per block (within this table)
    const int b = g >> 8;           // batch
    const bool EDGE = (tbl == 0);

    const float* table = EDGE ? tabE : tabS;
    const float* prox  = EDGE ? proxE : proxSen;
    const int NW = EDGE ? 6 : 4;

    // cooperative weight load into LDS
    for (int i2 = tid; i2 < NW*192; i2 += 256) {
        const int v = i2 / 192, e = (i2 % 192) * 4;
        const float* src = (v < 4) ? (prox + v*DIM + e) : ((v == 4) ? (wS + e) : (wE + e));
        *reinterpret_cast<float4*>(&wlds[v*DIM + e]) = *reinterpret_cast<const float4*>(src);
    }
    __syncthreads();

    const int rgrp = lane >> 3, sub = lane & 7;
    const int r0 = row0 + wib*16 + rgrp*2;      // this lane-group's two rows
    const float* rp0 = table + (size_t)r0 * DIM;
    const float* rp1 = rp0 + DIM;

    float xx0=0,d00=0,d01=0,d02=0,d03=0,dS0=0,dE0=0;
    float xx1=0,d10=0,d11=0,d12=0,d13=0,dS1=0,dE1=0;
    if (EDGE) kloop2<true >(rp0,rp1,wlds,sub,xx0,d00,d01,d02,d03,dS0,dE0,xx1,d10,d11,d12,d13,dS1,dE1);
    else      kloop2<false>(rp0,rp1,wlds,sub,xx0,d00,d01,d02,d03,dS0,dE0,xx1,d10,d11,d12,d13,dS1,dE1);

    // reduce across the 8-lane group (3 stages)
#pragma unroll
    for (int s = 1; s < 8; s <<= 1) {
        xx0+=__shfl_xor(xx0,s); d00+=__shfl_xor(d00,s); d01+=__shfl_xor(d01,s);
        d02+=__shfl_xor(d02,s); d03+=__shfl_xor(d03,s); dS0+=__shfl_xor(dS0,s); dE0+=__shfl_xor(dE0,s);
        xx1+=__shfl_xor(xx1,s); d10+=__shfl_xor(d10,s); d11+=__shfl_xor(d11,s);
        d12+=__shfl_xor(d12,s); d13+=__shfl_xor(d13,s); dS1+=__shfl_xor(dS1,s); dE1+=__shfl_xor(dE1,s);
    }
    if (sub == 0) {
        const int rr = wib*16 + rgrp*2;
        *reinterpret_cast<float2*>(&red[0*64+rr]) = make_float2(xx0, xx1);
        *reinterpret_cast<float2*>(&red[1*64+rr]) = make_float2(d00, d10);
        *reinterpret_cast<float2*>(&red[2*64+rr]) = make_float2(d01, d11);
        *reinterpret_cast<float2*>(&red[3*64+rr]) = make_float2(d02, d12);
        *reinterpret_cast<float2*>(&red[4*64+rr]) = make_float2(d03, d13);
        *reinterpret_cast<float2*>(&red[5*64+rr]) = make_float2(dS0, dS1);
        *reinterpret_cast<float2*>(&red[6*64+rr]) = make_float2(dE0, dE1);
    }
    __syncthreads();
    if (wib != 0) return;

    // ---------- wave 0 epilogue: 64 rows lane-parallel ----------
    int lens_i = attn[b*LSEQ + lane] + attn[b*LSEQ + 64 + lane];
#pragma unroll
    for (int s = 1; s < 64; s <<= 1) lens_i += __shfl_xor(lens_i, s);

    float pinv[NB];
#pragma unroll
    for (int c = 0; c < NB; ++c) {
        float s2 = 0.f;
#pragma unroll
        for (int t = 0; t < 12; ++t) { const float w = wlds[c*DIM + t*64 + lane]; s2 += w*w; }
        s2 = wave_reduce_f(s2);
        pinv[c] = 1.0f / fmaxf(sqrtf(s2), 1e-12f);
    }

    const int r = row0 + lane;      // row within this table [0,65536)
    const float xx = red[lane];
    float dd[NB] = { red[64+lane], red[128+lane], red[192+lane], red[256+lane] };
    const float xinv = 1.0f / fmaxf(sqrtf(xx), 1e-12f);
    const int i = r & (NLL - 1);
    const int l = i >> 7, m = i & (LSEQ - 1);
    const bool valid = (l >= 1) && (l < lens_i - 1) && (m >= 1) && (m < lens_i - 1);
    const int lab = (EDGE ? labE : labSen)[r];

    float Pa[NB] = {0,0,0,0}, Na[NB] = {0,0,0,0}, Ca[NB] = {0,0,0,0};
    if (valid) {
#pragma unroll
        for (int c = 0; c < NB; ++c) {
            const float cs = dd[c] * xinv * pinv[c];
            if (lab == c) { Pa[c] = expf(-ALPHA_C * (cs - MRG_C)); Ca[c] = 1.f; }
            else          { Na[c] = expf( ALPHA_C * (cs + MRG_C)); }
        }
    }
    float sBS = 0.f, sBE = 0.f;
    if (EDGE) {
        const float dS = red[320+lane], dE = red[384+lane];
        const float xSl = dS + bS[0], xEl = dE + bE[0];
        const int ls = tlabS[r], le = tlabE[r];
        const float w = (ls >= 0) ? 1.f : 0.f;
        const float spS = fmaxf(xSl, 0.f) + log1pf(expf(-fabsf(xSl)));
        const float spE = fmaxf(xEl, 0.f) + log1pf(expf(-fabsf(xEl)));
        sBS = w * (spS - xSl * (float)ls);
        sBE = w * (spE - xEl * (float)le);
        pS[r] = w / (1.f + expf(-xSl));
        pE[r] = w / (1.f + expf(-xEl));
    }

#pragma unroll
    for (int c = 0; c < NB; ++c) {
        Pa[c] = wave_reduce_f(Pa[c]); Na[c] = wave_reduce_f(Na[c]); Ca[c] = wave_reduce_f(Ca[c]);
    }
    sBS = wave_reduce_f(sBS); sBE = wave_reduce_f(sBE);

    if (lane == 0) {
        float* pp = EDGE ? partE : partSen;
        const int blk = g & (BPB - 1);
        const int base = b * 14;
#pragma unroll
        for (int c = 0; c < NB; ++c) {
            pp[(base + c)     * BPB + blk] = Pa[c];
            pp[(base + 4 + c) * BPB + blk] = Na[c];
            pp[(base + 8 + c) * BPB + blk] = Ca[c];
        }
        pp[(base + 12) * BPB + blk] = sBS;
        pp[(base + 13) * BPB + blk] = sBE;
    }
}

// 10 blocks: 0-7 = prune (exact k-th largest), 8-9 = finalize (scalar outputs).
__global__ __launch_bounds__(1024)
void tail_k(const float* __restrict__ pS, const float* __restrict__ pE,
            const int* __restrict__ attn,
            const float* __restrict__ partE, const float* __restrict__ partS,
            float* __restrict__ out)
{
    __shared__ unsigned sh[NLL];     // 64 KB (prune path)
    __shared__ int csum[16];
    __shared__ float gg[56];
    const int tid = threadIdx.x, wave = tid >> 6, lane = tid & 63;

    if (blockIdx.x >= 8) {
        const int tbl = blockIdx.x - 8;
        const float* part = (tbl == 0) ? partE : partS;
        for (int grp = wave; grp < 56; grp += 16) {
            float s = 0.f;
#pragma unroll
            for (int j = lane; j < BPB; j += 64) s += part[grp*BPB + j];
            s = wave_reduce_f(s);
            if (lane == 0) gg[grp] = s;
        }
        __syncthreads();
        if (tid == 0) {
            float tot = 0.f;
            for (int b = 0; b < NBATCH; ++b) {
                const float* G = gg + b * 14;
                int nv = 0;
                for (int c = 0; c < NB; ++c) nv += (G[8+c] > 0.f) ? 1 : 0;
                const float nvf = (float)((nv > 1) ? nv : 1);
                float pos = 0.f, neg = 0.f;
                for (int c = 0; c < NB; ++c) { pos += log1pf(G[c]); neg += log1pf(G[4+c]); }
                tot += pos / nvf + neg * 0.25f;
            }
            out[tbl] = CLW_C * tot * 0.25f;
            if (tbl == 0) {
                float bs = 0.f, be = 0.f;
                for (int b = 0; b < NBATCH; ++b) { bs += gg[b*14 + 12]; be += gg[b*14 + 13]; }
                out[2] = bs * (1.0f / 65536.0f);
                out[3] = be * (1.0f / 65536.0f);
            }
        }
        return;
    }

    const int a = blockIdx.x >> 2;   // 0 = S, 1 = E
    const int b = blockIdx.x & 3;
    const float* p = (a ? pE : pS) + (size_t)b * NLL;
    float* o = out + 4 + (size_t)a * (NBATCH * NLL) + (size_t)b * NLL;

    int asum = attn[b*LSEQ + lane] + attn[b*LSEQ + 64 + lane];
#pragma unroll
    for (int s = 1; s < 64; s <<= 1) asum += __shfl_xor(asum, s);
    const int mask_len = asum - 2;
    int k = (int)((float)mask_len * 0.3f);
    k = (k > 10) ? k : 10;
    const int ml2 = mask_len * mask_len;
    k = (k < ml2) ? k : ml2;

    for (int j = tid; j < NLL; j += 1024) sh[j] = __float_as_uint(p[j]);
    __syncthreads();

    unsigned lo = 0u, hi = 0xFFFFFFFFu;
    for (int it = 0; it < 32; ++it) {
        if (lo >= hi) break;                       // uniform across block
        const unsigned span = hi - lo;
        const unsigned mid = lo + (span >> 1) + (span & 1u);   // ceil midpoint, > lo
        int c = 0;
        for (int j = tid; j < NLL; j += 1024) c += (sh[j] >= mid) ? 1 : 0;
#pragma unroll
        for (int s = 1; s < 64; s <<= 1) c += __shfl_xor(c, s);
        if (lane == 0) csum[wave] = c;
        __syncthreads();
        int tot = 0;
#pragma unroll
        for (int w = 0; w < 16; ++w) tot += csum[w];
        if (tot >= k) lo = mid; else hi = mid - 1u;
        __syncthreads();
    }

    for (int j = tid; j < NLL; j += 1024) o[j] = (sh[j] >= lo) ? 1.0f : 0.0f;
}

extern "C" void kernel_launch(void* const* d_in, const int* in_sizes, int n_in,
                              void* d_out, int out_size, void* d_ws, size_t ws_size,
                              hipStream_t stream)
{
    const float* table_edge  = (const float*)d_in[0];
    const float* table_senti = (const float*)d_in[1];
    const int*   attn        = (const int*)d_in[2];
    const int*   tlabS       = (const int*)d_in[3];
    const int*   tlabE       = (const int*)d_in[4];
    const int*   lab_edge    = (const int*)d_in[5];
    const int*   lab_senti   = (const int*)d_in[6];
    const float* prox_edge   = (const float*)d_in[7];
    const float* prox_senti  = (const float*)d_in[8];
    const float* w_S         = (const float*)d_in[9];
    const float* b_S         = (const float*)d_in[10];
    const float* w_E         = (const float*)d_in[11];
    const float* b_E         = (const float*)d_in[12];

    float* out   = (float*)d_out;
    float* ws    = (float*)d_ws;
    float* pS    = ws;                      // 65536
    float* pE    = ws + 65536;              // 65536
    float* partE = ws + 131072;             // 4*14*256 = 14336
    float* partS = partE + 14336;           // 14336

    fused_pass<<<2048, 256, 0, stream>>>(table_edge, table_senti,
        lab_edge, lab_senti, attn, prox_edge, prox_senti,
        w_S, b_S, w_E, b_E, tlabS, tlabE, pS, pE, partE, partS);
    tail_k<<<10, 1024, 0, stream>>>(pS, pE, attn, partE, partS, out);
}